// Round 11
// baseline (285.505 us; speedup 1.0000x reference)
//
#include <hip/hip_runtime.h>
#include <hip/hip_bf16.h>
#include <cstdint>

#define B_  8
#define T_  128
#define S_  400
#define D_  512
#define V_  50000
#define M_  (B_*T_)          // 1024
#define NT_ 391              // col tiles in GEMM (391*128 >= 50000)
#define EPS_LN 1e-6f

#define WCONV_BLKS 12500
#define MW_BLKS    (B_*S_)   // 3200
#define ROWS_BLKS  M_        // 1024
#define BM_BLKS    B_        // 8 bitmap builders
#define BM_WORDS   1600      // words per batch (50000/32 = 1563, padded)

typedef __bf16 bf16x8 __attribute__((ext_vector_type(8)));
typedef float  f32x4  __attribute__((ext_vector_type(4)));
typedef unsigned short u16;
typedef unsigned short u16x8 __attribute__((ext_vector_type(8)));

__device__ __forceinline__ float bf2f(u16 u) {
    union { unsigned i; float f; } c; c.i = ((unsigned)u) << 16; return c.f;
}
__device__ __forceinline__ u16 f2bf(float f) {
    union { float f; unsigned i; } c; c.f = f;
    unsigned i = c.i;
    unsigned r = (i + 0x7FFFu + ((i >> 16) & 1u)) >> 16;   // round-nearest-even
    return (u16)r;
}

// block-wide reductions, blockDim.x == 256 (4 waves)
__device__ __forceinline__ float bsum(float v, float* sb) {
    #pragma unroll
    for (int o = 32; o; o >>= 1) v += __shfl_xor(v, o);
    __syncthreads();
    if ((threadIdx.x & 63) == 0) sb[threadIdx.x >> 6] = v;
    __syncthreads();
    return sb[0] + sb[1] + sb[2] + sb[3];
}

// K1 fused: [0,WCONV) proj_w f32->bf16 | [+MW) mw dots | [+ROWS) LN rows |
//           [+BM) per-batch src bitmap
__global__ void k_pre(const float* __restrict__ pw, u16* __restrict__ wb,
                      const float* __restrict__ mem, const float* __restrict__ whw,
                      float* __restrict__ mw,
                      const float* __restrict__ x, const float* __restrict__ xt,
                      const float* __restrict__ attn,
                      const float* __restrict__ na, const float* __restrict__ nb,
                      const float* __restrict__ wsw, const float* __restrict__ wxw,
                      const float* __restrict__ whb, const float* __restrict__ wsb,
                      const float* __restrict__ wxb, const float* __restrict__ bp,
                      const int* __restrict__ src, unsigned* __restrict__ bm,
                      u16* __restrict__ Ab, float* __restrict__ pgen,
                      float* __restrict__ outp) {
    __shared__ float sb[4];
    __shared__ unsigned sbm[BM_WORDS];
    int bid = blockIdx.x;
    int tid = threadIdx.x;
    if (bid < WCONV_BLKS) {
        size_t i = ((size_t)bid * 256 + tid) * 8;
        float4 a = *(const float4*)(pw + i);
        float4 b = *(const float4*)(pw + i + 4);
        u16x8 o;
        o[0] = f2bf(a.x); o[1] = f2bf(a.y); o[2] = f2bf(a.z); o[3] = f2bf(a.w);
        o[4] = f2bf(b.x); o[5] = f2bf(b.y); o[6] = f2bf(b.z); o[7] = f2bf(b.w);
        *(u16x8*)(wb + i) = o;
        return;
    }
    if (bid < WCONV_BLKS + MW_BLKS) {
        int row = bid - WCONV_BLKS;               // b*S + s
        const float* mr = mem + (size_t)row * D_;
        float2 m2 = *(const float2*)(mr + tid * 2);
        float2 w2 = *(const float2*)(whw + tid * 2);
        float tot = bsum(m2.x * w2.x + m2.y * w2.y, sb);
        if (tid == 0) mw[row] = tot;
        return;
    }
    if (bid < WCONV_BLKS + MW_BLKS + ROWS_BLKS) {
        int row = bid - WCONV_BLKS - MW_BLKS;     // b*T + t
        int b = row / T_;
        const float* xr  = x  + (size_t)row * D_;
        const float* xtr = xt + (size_t)row * D_;
        float2 xv = *(const float2*)(xr + tid * 2);
        float tsx  = bsum(xv.x + xv.y, sb);
        float tsx2 = bsum(xv.x * xv.x + xv.y * xv.y, sb);
        float mu  = tsx / (float)D_;
        float var = fmaxf(tsx2 / (float)D_ - mu * mu, 0.f);
        float rs  = 1.f / (sqrtf(var) + EPS_LN);
        float2 nav = *(const float2*)(na + tid * 2);
        float2 nbv = *(const float2*)(nb + tid * 2);
        u16 a0 = f2bf(nav.x * (xv.x - mu) * rs + nbv.x);
        u16 a1 = f2bf(nav.y * (xv.y - mu) * rs + nbv.y);
        ((unsigned*)(Ab + (size_t)row * D_))[tid] = (unsigned)a0 | ((unsigned)a1 << 16);
        float2 wsv = *(const float2*)(wsw + tid * 2);
        float2 wxv = *(const float2*)(wxw + tid * 2);
        float2 xtv = *(const float2*)(xtr + tid * 2);
        float dot = xv.x * wsv.x + xv.y * wsv.y + xtv.x * wxv.x + xtv.y * wxv.y;
        if (tid < 200) {
            const float* ar  = attn + (size_t)row * S_;
            const float* mwb = mw + b * S_;
            float2 av = *(const float2*)(ar + tid * 2);
            float2 mv = *(const float2*)(mwb + tid * 2);
            dot += av.x * mv.x + av.y * mv.y;
        }
        float tdot = bsum(dot, sb);
        if (tid == 0) {
            float logit = tdot + whb[0] + wsb[0] + wxb[0] + bp[0];
            float p = 1.f / (1.f + __expf(-logit));
            pgen[row] = p;
            outp[row] = p;
        }
        return;
    }
    {   // bitmap builder: one block per batch b
        int b = bid - WCONV_BLKS - MW_BLKS - ROWS_BLKS;
        for (int i = tid; i < BM_WORDS; i += 256) sbm[i] = 0u;
        __syncthreads();
        const int* sr = src + b * S_;
        for (int s = tid; s < S_; s += 256) {
            int v = sr[s];
            atomicOr(&sbm[v >> 5], 1u << (v & 31));
        }
        __syncthreads();
        unsigned* dst = bm + b * BM_WORDS;
        for (int i = tid; i < BM_WORDS; i += 256) dst[i] = sbm[i];
    }
}

// K2: dec[m,v] = A[m,:] . W[v,:] + proj_b[v].
// 128x128 tile, 4 waves, depth-3 pipelined K-loop (best measured: 118.7us),
// ONE barrier per step, counted vmcnt. Fragment-major LDS (conflict-free
// ds_read_b128), LDS-staged coalesced output, fused sum-exp partials.
__global__ __launch_bounds__(256) void k_gemm(const u16* __restrict__ Ab,
                                              const u16* __restrict__ Wb,
                                              const float* __restrict__ projb,
                                              u16* __restrict__ dec,
                                              float* __restrict__ psum) {
    __shared__ __align__(16) char smem[49152];    // 3 x 16KB (A 8K + B 8K)
    int bid = blockIdx.x;
    int xcd = bid & 7, loc = bid >> 3;
    int wg = xcd * NT_ + loc;             // bijective: 3128 = 8*391
    int mt = wg & 7, nt = wg >> 3;
    int brow = mt * 128, bcol = nt * 128;
    int tid = threadIdx.x, lane = tid & 63, wv = tid >> 6;
    int wm = wv >> 1, wn = wv & 1;
    int kq = lane >> 4, lr = lane & 15;

    // per-thread staging source offsets (fragment-major pre-permutation, m173)
    size_t aoff[2], boff[2];
    int flatoff[2];
    #pragma unroll
    for (int i = 0; i < 2; ++i) {
        int flat = i * 4096 + tid * 16;            // bytes into 8KB half
        flatoff[i] = flat;
        int sub = flat >> 10;                      // 16-row subtile 0..7
        int l   = (flat >> 4) & 63;                // lane slot in subtile
        int kq2 = l >> 4, lr2 = l & 15;
        int arow = brow + sub * 16 + lr2;
        int vrow = bcol + sub * 16 + lr2; if (vrow >= V_) vrow = V_ - 1;
        aoff[i] = (size_t)arow * 512 + kq2 * 8;
        boff[i] = (size_t)vrow * 512 + kq2 * 8;
    }

#define STAGE(buf, kt) { \
    char* ab = smem + (buf) * 16384; \
    _Pragma("unroll") \
    for (int i = 0; i < 2; ++i) { \
        __builtin_amdgcn_global_load_lds( \
            (const __attribute__((address_space(1))) unsigned*)(Ab + aoff[i] + (size_t)(kt) * 32), \
            (__attribute__((address_space(3))) unsigned*)(ab + flatoff[i]), 16, 0, 0); \
        __builtin_amdgcn_global_load_lds( \
            (const __attribute__((address_space(1))) unsigned*)(Wb + boff[i] + (size_t)(kt) * 32), \
            (__attribute__((address_space(3))) unsigned*)(ab + 8192 + flatoff[i]), 16, 0, 0); \
    } }

    f32x4 acc[4][4] = {};
    STAGE(0, 0);
    STAGE(1, 1);
    STAGE(2, 2);                                   // 12 outstanding / thread
    asm volatile("s_waitcnt vmcnt(8)" ::: "memory");   // tile 0 landed
    __builtin_amdgcn_s_barrier();
    __builtin_amdgcn_sched_barrier(0);
    int cur = 0;
    for (int kt = 0; kt < 16; ++kt) {
        const bf16x8* Afp = (const bf16x8*)(smem + cur * 16384);
        const bf16x8* Bfp = (const bf16x8*)(smem + cur * 16384 + 8192);
        bf16x8 af[4], bfr[4];
        #pragma unroll
        for (int m = 0; m < 4; ++m) af[m]  = Afp[(wm * 4 + m) * 64 + lane];
        #pragma unroll
        for (int n = 0; n < 4; ++n) bfr[n] = Bfp[(wn * 4 + n) * 64 + lane];
        #pragma unroll
        for (int m = 0; m < 4; ++m)
            #pragma unroll
            for (int n = 0; n < 4; ++n)
                acc[m][n] = __builtin_amdgcn_mfma_f32_16x16x32_bf16(af[m], bfr[n], acc[m][n], 0, 0, 0);
        __builtin_amdgcn_sched_barrier(0);
        if (kt == 15) break;
        if (kt < 14) { asm volatile("s_waitcnt vmcnt(4)" ::: "memory"); }
        else         { asm volatile("s_waitcnt vmcnt(0)" ::: "memory"); }
        __builtin_amdgcn_s_barrier();
        __builtin_amdgcn_sched_barrier(0);
        if (kt < 13) STAGE(cur, kt + 3);
        cur = (cur == 2) ? 0 : cur + 1;
    }
#undef STAGE
    __syncthreads();                               // all frag reads done before Os reuse

    // epilogue: bias, sum-exp partials (no max: |dec| < ~8), Os staging for
    // coalesced stores
    float pbn[4]; int cvaln[4];
    #pragma unroll
    for (int n = 0; n < 4; ++n) {
        int col = bcol + wn * 64 + n * 16 + lr;
        cvaln[n] = (col < V_);
        pbn[n] = cvaln[n] ? projb[col] : 0.f;
    }
    u16 (*Os)[136] = (u16(*)[136])smem;
    float* ssum = (float*)(smem + 34816);          // [2][128]
    #pragma unroll
    for (int m = 0; m < 4; ++m) {
        #pragma unroll
        for (int i = 0; i < 4; ++i) {
            int row128 = wm * 64 + m * 16 + kq * 4 + i;
            float se = 0.f;
            #pragma unroll
            for (int n = 0; n < 4; ++n) {
                float dv = acc[m][n][i] + pbn[n];
                if (cvaln[n]) se += __expf(dv);
                Os[row128][wn * 64 + n * 16 + lr] = f2bf(dv);
            }
            #pragma unroll
            for (int o = 1; o < 16; o <<= 1) se += __shfl_xor(se, o);
            if (lr == 0) ssum[wn * 128 + row128] = se;
        }
    }
    __syncthreads();
    if (tid < 128) {
        psum[(size_t)(brow + tid) * NT_ + nt] = ssum[tid] + ssum[128 + tid];
    }
    #pragma unroll
    for (int j = 0; j < 8; ++j) {
        int row = j * 16 + (tid >> 4);
        int c8 = (tid & 15) * 8;
        int gcol = bcol + c8;
        if (gcol + 8 <= V_) {                      // V_ % 8 == 0: chunk all-or-nothing
            u16x8 v = *(const u16x8*)&Os[row][c8];
            *(u16x8*)(dec + (size_t)(brow + row) * V_ + gcol) = v;
        }
    }
}

// K3 merged: [0,1024) = fix blocks (pointer-mix on src columns, runs first);
// [1024, 1024+25600) = final blocks: out = d + C, SKIPPING src columns
// (bitmap test) so there is no write-write race with fix blocks.
__global__ void k_post(const u16* __restrict__ dec, const float* __restrict__ pgen,
                       const float* __restrict__ psum, const unsigned* __restrict__ bm,
                       const int* __restrict__ src, const float* __restrict__ attn,
                       float* __restrict__ out) {
    __shared__ float sb[4];
    __shared__ int   sh_sr[S_];
    __shared__ int   sh_fs[S_];
    __shared__ float sh_enc[S_];
    int bid = blockIdx.x;
    int tid = threadIdx.x;
    if (bid < M_) {
        // ---- fix block: one per (b,t) row ----
        int b = bid >> 7;
        int row = bid;
        const float* ps = psum + (size_t)row * NT_;
        float s = 0.f;
        for (int j = tid; j < NT_; j += 256) s += ps[j];
        s = bsum(s, sb);
        float bs = __logf(s);
        const int* sr = src + b * S_;
        for (int s2 = tid; s2 < S_; s2 += 256) { sh_sr[s2] = sr[s2]; sh_enc[s2] = 0.f; }
        __syncthreads();
        for (int s2 = tid; s2 < S_; s2 += 256) {
            int v = sh_sr[s2];
            int f = 0;
            while (sh_sr[f] != v) ++f;    // first occurrence (terminates at s2)
            sh_fs[s2] = f;
        }
        __syncthreads();
        const float* ar = attn + (size_t)row * S_;
        for (int s2 = tid; s2 < S_; s2 += 256)
            atomicAdd(&sh_enc[sh_fs[s2]], ar[s2]);
        __syncthreads();
        float p = pgen[row];
        for (int s2 = tid; s2 < S_; s2 += 256) {
            if (sh_fs[s2] == s2) {
                int v = sh_sr[s2];
                float d = bf2f(dec[(size_t)row * V_ + v]);
                out[(size_t)row * V_ + v] =
                    __logf(p * __expf(d - bs) + (1.f - p) * sh_enc[s2] + 1e-12f);
            }
        }
        return;
    }
    // ---- final block ----
    int fid = bid - M_;                   // 0..25599
    int c = fid % 25, row = fid / 25;
    int b = row >> 7;
    const float* ps = psum + (size_t)row * NT_;
    float s = 0.f;
    for (int j = tid; j < NT_; j += 256) s += ps[j];
    s = bsum(s, sb);
    float C = __logf(pgen[row]) - __logf(s);
    int v0 = c * 2048 + tid * 8;
    if (v0 >= V_) return;
    unsigned w = bm[b * BM_WORDS + (v0 >> 5)];
    unsigned mask = (w >> ((tid & 3) * 8)) & 0xFFu;
    u16x8 d = *(const u16x8*)(dec + (size_t)row * V_ + v0);
    float o[8];
    bool rare = false;
    #pragma unroll
    for (int j = 0; j < 8; ++j) {
        o[j] = bf2f(d[j]) + C;
        rare |= (o[j] < -24.f);
    }
    if (__any(rare)) {                    // wave-uniform: skipped ~always
        #pragma unroll
        for (int j = 0; j < 8; ++j)
            if (o[j] < -24.f) o[j] = __logf(__expf(o[j]) + 1e-12f);
    }
    float* op = out + (size_t)row * V_ + v0;
    if (__any(mask != 0)) {               // rare: some lane overlaps src columns
        #pragma unroll
        for (int j = 0; j < 8; ++j)
            if (!((mask >> j) & 1u)) op[j] = o[j];
    } else {
        float4 o0, o1;
        o0.x = o[0]; o0.y = o[1]; o0.z = o[2]; o0.w = o[3];
        o1.x = o[4]; o1.y = o[5]; o1.z = o[6]; o1.w = o[7];
        *(float4*)op = o0;
        *(float4*)(op + 4) = o1;
    }
}

extern "C" void kernel_launch(void* const* d_in, const int* in_sizes, int n_in,
                              void* d_out, int out_size, void* d_ws, size_t ws_size,
                              hipStream_t stream) {
    const float* x    = (const float*)d_in[0];
    const float* xt   = (const float*)d_in[1];
    const float* mem  = (const float*)d_in[2];
    const float* attn = (const float*)d_in[3];
    const int*   src  = (const int*)d_in[4];
    const float* na   = (const float*)d_in[5];
    const float* nb   = (const float*)d_in[6];
    const float* pw   = (const float*)d_in[7];
    const float* pb   = (const float*)d_in[8];
    const float* whw  = (const float*)d_in[9];
    const float* whb  = (const float*)d_in[10];
    const float* wsw  = (const float*)d_in[11];
    const float* wsb  = (const float*)d_in[12];
    const float* wxw  = (const float*)d_in[13];
    const float* wxb  = (const float*)d_in[14];
    const float* bp   = (const float*)d_in[15];

    char* ws = (char*)d_ws;
    u16*     Wb   = (u16*)(ws + 0);               // 51,200,000 B
    u16*     Ab   = (u16*)(ws + 51200000);        //  1,048,576 B
    u16*     dec  = (u16*)(ws + 52248576);        // 102,400,000 B
    float*   psum = (float*)(ws + 154648576);     //  1,601,536 B
    float*   mw   = (float*)(ws + 156250112);     //     12,800 B
    float*   pgen = (float*)(ws + 156262912);     //      4,096 B
    unsigned* bmp = (unsigned*)(ws + 156267008);  //     51,200 B
    float* out  = (float*)d_out;
    float* outp = out + (size_t)M_ * V_;          // p_gen section

    k_pre <<<WCONV_BLKS + MW_BLKS + ROWS_BLKS + BM_BLKS, 256, 0, stream>>>(
              pw, Wb, mem, whw, mw, x, xt, attn, na, nb,
              wsw, wxw, whb, wsb, wxb, bp, src, bmp, Ab, pgen, outp);
    k_gemm<<<3128, 256, 0, stream>>>(Ab, Wb, pb, dec, psum);
    k_post<<<M_ + 25 * M_, 256, 0, stream>>>(dec, pgen, psum, bmp, src, attn, out);
}

// Round 12
// 285.247 us; speedup vs baseline: 1.0009x; 1.0009x over previous
//
#include <hip/hip_runtime.h>
#include <hip/hip_bf16.h>
#include <cstdint>

#define B_  8
#define T_  128
#define S_  400
#define D_  512
#define V_  50000
#define M_  (B_*T_)          // 1024
#define NT_ 391              // col tiles in GEMM (391*128 >= 50000)
#define EPS_LN 1e-6f

#define WCONV_BLKS 12500
#define MW_BLKS    (B_*S_)   // 3200
#define ROWS_BLKS  M_        // 1024
#define BM_BLKS    B_        // 8 bitmap builders
#define BM_WORDS   1600      // words per batch (50000/32 = 1563, padded)

typedef __bf16 bf16x8 __attribute__((ext_vector_type(8)));
typedef float  f32x4  __attribute__((ext_vector_type(4)));
typedef unsigned short u16;
typedef unsigned short u16x8 __attribute__((ext_vector_type(8)));

__device__ __forceinline__ float bf2f(u16 u) {
    union { unsigned i; float f; } c; c.i = ((unsigned)u) << 16; return c.f;
}
__device__ __forceinline__ u16 f2bf(float f) {
    union { float f; unsigned i; } c; c.f = f;
    unsigned i = c.i;
    unsigned r = (i + 0x7FFFu + ((i >> 16) & 1u)) >> 16;   // round-nearest-even
    return (u16)r;
}

// block-wide reductions, blockDim.x == 256 (4 waves)
__device__ __forceinline__ float bsum(float v, float* sb) {
    #pragma unroll
    for (int o = 32; o; o >>= 1) v += __shfl_xor(v, o);
    __syncthreads();
    if ((threadIdx.x & 63) == 0) sb[threadIdx.x >> 6] = v;
    __syncthreads();
    return sb[0] + sb[1] + sb[2] + sb[3];
}

// K1 fused: [0,WCONV) proj_w f32->bf16 | [+MW) mw dots | [+ROWS) LN rows |
//           [+BM) per-batch src bitmap
__global__ void k_pre(const float* __restrict__ pw, u16* __restrict__ wb,
                      const float* __restrict__ mem, const float* __restrict__ whw,
                      float* __restrict__ mw,
                      const float* __restrict__ x, const float* __restrict__ xt,
                      const float* __restrict__ attn,
                      const float* __restrict__ na, const float* __restrict__ nb,
                      const float* __restrict__ wsw, const float* __restrict__ wxw,
                      const float* __restrict__ whb, const float* __restrict__ wsb,
                      const float* __restrict__ wxb, const float* __restrict__ bp,
                      const int* __restrict__ src, unsigned* __restrict__ bm,
                      u16* __restrict__ Ab, float* __restrict__ pgen,
                      float* __restrict__ outp) {
    __shared__ float sb[4];
    __shared__ unsigned sbm[BM_WORDS];
    int bid = blockIdx.x;
    int tid = threadIdx.x;
    if (bid < WCONV_BLKS) {
        size_t i = ((size_t)bid * 256 + tid) * 8;
        float4 a = *(const float4*)(pw + i);
        float4 b = *(const float4*)(pw + i + 4);
        u16x8 o;
        o[0] = f2bf(a.x); o[1] = f2bf(a.y); o[2] = f2bf(a.z); o[3] = f2bf(a.w);
        o[4] = f2bf(b.x); o[5] = f2bf(b.y); o[6] = f2bf(b.z); o[7] = f2bf(b.w);
        *(u16x8*)(wb + i) = o;
        return;
    }
    if (bid < WCONV_BLKS + MW_BLKS) {
        int row = bid - WCONV_BLKS;               // b*S + s
        const float* mr = mem + (size_t)row * D_;
        float2 m2 = *(const float2*)(mr + tid * 2);
        float2 w2 = *(const float2*)(whw + tid * 2);
        float tot = bsum(m2.x * w2.x + m2.y * w2.y, sb);
        if (tid == 0) mw[row] = tot;
        return;
    }
    if (bid < WCONV_BLKS + MW_BLKS + ROWS_BLKS) {
        int row = bid - WCONV_BLKS - MW_BLKS;     // b*T + t
        int b = row / T_;
        const float* xr  = x  + (size_t)row * D_;
        const float* xtr = xt + (size_t)row * D_;
        float2 xv = *(const float2*)(xr + tid * 2);
        float tsx  = bsum(xv.x + xv.y, sb);
        float tsx2 = bsum(xv.x * xv.x + xv.y * xv.y, sb);
        float mu  = tsx / (float)D_;
        float var = fmaxf(tsx2 / (float)D_ - mu * mu, 0.f);
        float rs  = 1.f / (sqrtf(var) + EPS_LN);
        float2 nav = *(const float2*)(na + tid * 2);
        float2 nbv = *(const float2*)(nb + tid * 2);
        u16 a0 = f2bf(nav.x * (xv.x - mu) * rs + nbv.x);
        u16 a1 = f2bf(nav.y * (xv.y - mu) * rs + nbv.y);
        ((unsigned*)(Ab + (size_t)row * D_))[tid] = (unsigned)a0 | ((unsigned)a1 << 16);
        float2 wsv = *(const float2*)(wsw + tid * 2);
        float2 wxv = *(const float2*)(wxw + tid * 2);
        float2 xtv = *(const float2*)(xtr + tid * 2);
        float dot = xv.x * wsv.x + xv.y * wsv.y + xtv.x * wxv.x + xtv.y * wxv.y;
        if (tid < 200) {
            const float* ar  = attn + (size_t)row * S_;
            const float* mwb = mw + b * S_;
            float2 av = *(const float2*)(ar + tid * 2);
            float2 mv = *(const float2*)(mwb + tid * 2);
            dot += av.x * mv.x + av.y * mv.y;
        }
        float tdot = bsum(dot, sb);
        if (tid == 0) {
            float logit = tdot + whb[0] + wsb[0] + wxb[0] + bp[0];
            float p = 1.f / (1.f + __expf(-logit));
            pgen[row] = p;
            outp[row] = p;
        }
        return;
    }
    {   // bitmap builder: one block per batch b
        int b = bid - WCONV_BLKS - MW_BLKS - ROWS_BLKS;
        for (int i = tid; i < BM_WORDS; i += 256) sbm[i] = 0u;
        __syncthreads();
        const int* sr = src + b * S_;
        for (int s = tid; s < S_; s += 256) {
            int v = sr[s];
            atomicOr(&sbm[v >> 5], 1u << (v & 31));
        }
        __syncthreads();
        unsigned* dst = bm + b * BM_WORDS;
        for (int i = tid; i < BM_WORDS; i += 256) dst[i] = sbm[i];
    }
}

// K2: dec[m,v] = A[m,:] . W[v,:] + proj_b[v].
// 128x128 tile, 4 waves, depth-3 pipelined K-loop (best measured: 118.7us),
// ONE barrier per step, counted vmcnt. Fragment-major LDS (conflict-free
// ds_read_b128), LDS-staged coalesced output, fused sum-exp partials.
__global__ __launch_bounds__(256) void k_gemm(const u16* __restrict__ Ab,
                                              const u16* __restrict__ Wb,
                                              const float* __restrict__ projb,
                                              u16* __restrict__ dec,
                                              float* __restrict__ psum) {
    __shared__ __align__(16) char smem[49152];    // 3 x 16KB (A 8K + B 8K)
    int bid = blockIdx.x;
    int xcd = bid & 7, loc = bid >> 3;
    int wg = xcd * NT_ + loc;             // bijective: 3128 = 8*391
    int mt = wg & 7, nt = wg >> 3;
    int brow = mt * 128, bcol = nt * 128;
    int tid = threadIdx.x, lane = tid & 63, wv = tid >> 6;
    int wm = wv >> 1, wn = wv & 1;
    int kq = lane >> 4, lr = lane & 15;

    // per-thread staging source offsets (fragment-major pre-permutation, m173)
    size_t aoff[2], boff[2];
    int flatoff[2];
    #pragma unroll
    for (int i = 0; i < 2; ++i) {
        int flat = i * 4096 + tid * 16;            // bytes into 8KB half
        flatoff[i] = flat;
        int sub = flat >> 10;                      // 16-row subtile 0..7
        int l   = (flat >> 4) & 63;                // lane slot in subtile
        int kq2 = l >> 4, lr2 = l & 15;
        int arow = brow + sub * 16 + lr2;
        int vrow = bcol + sub * 16 + lr2; if (vrow >= V_) vrow = V_ - 1;
        aoff[i] = (size_t)arow * 512 + kq2 * 8;
        boff[i] = (size_t)vrow * 512 + kq2 * 8;
    }

#define STAGE(buf, kt) { \
    char* ab = smem + (buf) * 16384; \
    _Pragma("unroll") \
    for (int i = 0; i < 2; ++i) { \
        __builtin_amdgcn_global_load_lds( \
            (const __attribute__((address_space(1))) unsigned*)(Ab + aoff[i] + (size_t)(kt) * 32), \
            (__attribute__((address_space(3))) unsigned*)(ab + flatoff[i]), 16, 0, 0); \
        __builtin_amdgcn_global_load_lds( \
            (const __attribute__((address_space(1))) unsigned*)(Wb + boff[i] + (size_t)(kt) * 32), \
            (__attribute__((address_space(3))) unsigned*)(ab + 8192 + flatoff[i]), 16, 0, 0); \
    } }

    f32x4 acc[4][4] = {};
    STAGE(0, 0);
    STAGE(1, 1);
    STAGE(2, 2);                                   // 12 outstanding / thread
    asm volatile("s_waitcnt vmcnt(8)" ::: "memory");   // tile 0 landed
    __builtin_amdgcn_s_barrier();
    __builtin_amdgcn_sched_barrier(0);
    int cur = 0;
    for (int kt = 0; kt < 16; ++kt) {
        const bf16x8* Afp = (const bf16x8*)(smem + cur * 16384);
        const bf16x8* Bfp = (const bf16x8*)(smem + cur * 16384 + 8192);
        bf16x8 af[4], bfr[4];
        #pragma unroll
        for (int m = 0; m < 4; ++m) af[m]  = Afp[(wm * 4 + m) * 64 + lane];
        #pragma unroll
        for (int n = 0; n < 4; ++n) bfr[n] = Bfp[(wn * 4 + n) * 64 + lane];
        #pragma unroll
        for (int m = 0; m < 4; ++m)
            #pragma unroll
            for (int n = 0; n < 4; ++n)
                acc[m][n] = __builtin_amdgcn_mfma_f32_16x16x32_bf16(af[m], bfr[n], acc[m][n], 0, 0, 0);
        __builtin_amdgcn_sched_barrier(0);
        if (kt == 15) break;
        if (kt < 14) { asm volatile("s_waitcnt vmcnt(4)" ::: "memory"); }
        else         { asm volatile("s_waitcnt vmcnt(0)" ::: "memory"); }
        __builtin_amdgcn_s_barrier();
        __builtin_amdgcn_sched_barrier(0);
        if (kt < 13) STAGE(cur, kt + 3);
        cur = (cur == 2) ? 0 : cur + 1;
    }
#undef STAGE
    __syncthreads();                               // all frag reads done before Os reuse

    // epilogue: bias, sum-exp partials (no max: |dec| < ~8), Os staging for
    // coalesced stores
    float pbn[4]; int cvaln[4];
    #pragma unroll
    for (int n = 0; n < 4; ++n) {
        int col = bcol + wn * 64 + n * 16 + lr;
        cvaln[n] = (col < V_);
        pbn[n] = cvaln[n] ? projb[col] : 0.f;
    }
    u16 (*Os)[136] = (u16(*)[136])smem;
    float* ssum = (float*)(smem + 34816);          // [2][128]
    #pragma unroll
    for (int m = 0; m < 4; ++m) {
        #pragma unroll
        for (int i = 0; i < 4; ++i) {
            int row128 = wm * 64 + m * 16 + kq * 4 + i;
            float se = 0.f;
            #pragma unroll
            for (int n = 0; n < 4; ++n) {
                float dv = acc[m][n][i] + pbn[n];
                if (cvaln[n]) se += __expf(dv);
                Os[row128][wn * 64 + n * 16 + lr] = f2bf(dv);
            }
            #pragma unroll
            for (int o = 1; o < 16; o <<= 1) se += __shfl_xor(se, o);
            if (lr == 0) ssum[wn * 128 + row128] = se;
        }
    }
    __syncthreads();
    if (tid < 128) {
        psum[(size_t)(brow + tid) * NT_ + nt] = ssum[tid] + ssum[128 + tid];
    }
    #pragma unroll
    for (int j = 0; j < 8; ++j) {
        int row = j * 16 + (tid >> 4);
        int c8 = (tid & 15) * 8;
        int gcol = bcol + c8;
        if (gcol + 8 <= V_) {                      // V_ % 8 == 0: chunk all-or-nothing
            u16x8 v = *(const u16x8*)&Os[row][c8];
            *(u16x8*)(dec + (size_t)(brow + row) * V_ + gcol) = v;
        }
    }
}

// K3 merged: [0,1024) = fix blocks (pointer-mix on src columns, runs first);
// [1024, 1024+25600) = final blocks: out = d + C, SKIPPING src columns
// (bitmap test) so there is no write-write race with fix blocks.
__global__ void k_post(const u16* __restrict__ dec, const float* __restrict__ pgen,
                       const float* __restrict__ psum, const unsigned* __restrict__ bm,
                       const int* __restrict__ src, const float* __restrict__ attn,
                       float* __restrict__ out) {
    __shared__ float sb[4];
    __shared__ int   sh_sr[S_];
    __shared__ int   sh_fs[S_];
    __shared__ float sh_enc[S_];
    int bid = blockIdx.x;
    int tid = threadIdx.x;
    if (bid < M_) {
        // ---- fix block: one per (b,t) row ----
        int b = bid >> 7;
        int row = bid;
        const float* ps = psum + (size_t)row * NT_;
        float s = 0.f;
        for (int j = tid; j < NT_; j += 256) s += ps[j];
        s = bsum(s, sb);
        float bs = __logf(s);
        const int* sr = src + b * S_;
        for (int s2 = tid; s2 < S_; s2 += 256) { sh_sr[s2] = sr[s2]; sh_enc[s2] = 0.f; }
        __syncthreads();
        for (int s2 = tid; s2 < S_; s2 += 256) {
            int v = sh_sr[s2];
            int f = 0;
            while (sh_sr[f] != v) ++f;    // first occurrence (terminates at s2)
            sh_fs[s2] = f;
        }
        __syncthreads();
        const float* ar = attn + (size_t)row * S_;
        for (int s2 = tid; s2 < S_; s2 += 256)
            atomicAdd(&sh_enc[sh_fs[s2]], ar[s2]);
        __syncthreads();
        float p = pgen[row];
        for (int s2 = tid; s2 < S_; s2 += 256) {
            if (sh_fs[s2] == s2) {
                int v = sh_sr[s2];
                float d = bf2f(dec[(size_t)row * V_ + v]);
                out[(size_t)row * V_ + v] =
                    __logf(p * __expf(d - bs) + (1.f - p) * sh_enc[s2] + 1e-12f);
            }
        }
        return;
    }
    // ---- final block ----
    int fid = bid - M_;                   // 0..25599
    int c = fid % 25, row = fid / 25;
    int b = row >> 7;
    const float* ps = psum + (size_t)row * NT_;
    float s = 0.f;
    for (int j = tid; j < NT_; j += 256) s += ps[j];
    s = bsum(s, sb);
    float C = __logf(pgen[row]) - __logf(s);
    int v0 = c * 2048 + tid * 8;
    if (v0 >= V_) return;
    unsigned w = bm[b * BM_WORDS + (v0 >> 5)];
    unsigned mask = (w >> ((tid & 3) * 8)) & 0xFFu;
    u16x8 d = *(const u16x8*)(dec + (size_t)row * V_ + v0);
    float o[8];
    bool rare = false;
    #pragma unroll
    for (int j = 0; j < 8; ++j) {
        o[j] = bf2f(d[j]) + C;
        rare |= (o[j] < -24.f);
    }
    if (__any(rare)) {                    // wave-uniform: skipped ~always
        #pragma unroll
        for (int j = 0; j < 8; ++j)
            if (o[j] < -24.f) o[j] = __logf(__expf(o[j]) + 1e-12f);
    }
    float* op = out + (size_t)row * V_ + v0;
    if (__any(mask != 0)) {               // rare: some lane overlaps src columns
        #pragma unroll
        for (int j = 0; j < 8; ++j)
            if (!((mask >> j) & 1u)) op[j] = o[j];
    } else {
        float4 o0, o1;
        o0.x = o[0]; o0.y = o[1]; o0.z = o[2]; o0.w = o[3];
        o1.x = o[4]; o1.y = o[5]; o1.z = o[6]; o1.w = o[7];
        *(float4*)op = o0;
        *(float4*)(op + 4) = o1;
    }
}

extern "C" void kernel_launch(void* const* d_in, const int* in_sizes, int n_in,
                              void* d_out, int out_size, void* d_ws, size_t ws_size,
                              hipStream_t stream) {
    const float* x    = (const float*)d_in[0];
    const float* xt   = (const float*)d_in[1];
    const float* mem  = (const float*)d_in[2];
    const float* attn = (const float*)d_in[3];
    const int*   src  = (const int*)d_in[4];
    const float* na   = (const float*)d_in[5];
    const float* nb   = (const float*)d_in[6];
    const float* pw   = (const float*)d_in[7];
    const float* pb   = (const float*)d_in[8];
    const float* whw  = (const float*)d_in[9];
    const float* whb  = (const float*)d_in[10];
    const float* wsw  = (const float*)d_in[11];
    const float* wsb  = (const float*)d_in[12];
    const float* wxw  = (const float*)d_in[13];
    const float* wxb  = (const float*)d_in[14];
    const float* bp   = (const float*)d_in[15];

    char* ws = (char*)d_ws;
    u16*     Wb   = (u16*)(ws + 0);               // 51,200,000 B
    u16*     Ab   = (u16*)(ws + 51200000);        //  1,048,576 B
    u16*     dec  = (u16*)(ws + 52248576);        // 102,400,000 B
    float*   psum = (float*)(ws + 154648576);     //  1,601,536 B
    float*   mw   = (float*)(ws + 156250112);     //     12,800 B
    float*   pgen = (float*)(ws + 156262912);     //      4,096 B
    unsigned* bmp = (unsigned*)(ws + 156267008);  //     51,200 B
    float* out  = (float*)d_out;
    float* outp = out + (size_t)M_ * V_;          // p_gen section

    k_pre <<<WCONV_BLKS + MW_BLKS + ROWS_BLKS + BM_BLKS, 256, 0, stream>>>(
              pw, Wb, mem, whw, mw, x, xt, attn, na, nb,
              wsw, wxw, whb, wsb, wxb, bp, src, bmp, Ab, pgen, outp);
    k_gemm<<<3128, 256, 0, stream>>>(Ab, Wb, pb, dec, psum);
    k_post<<<M_ + 25 * M_, 256, 0, stream>>>(dec, pgen, psum, bmp, src, attn, out);
}

// Round 13
// 222.132 us; speedup vs baseline: 1.2853x; 1.2841x over previous
//
#include <hip/hip_runtime.h>
#include <hip/hip_bf16.h>
#include <cstdint>

#define B_  8
#define T_  128
#define S_  400
#define D_  512
#define V_  50000
#define M_  (B_*T_)          // 1024
#define NT_ 391              // col tiles in GEMM (391*128 >= 50000)
#define EPS_LN 1e-6f

#define WCONV_BLKS 12500
#define MW_BLKS    (B_*S_)   // 3200
#define ROWS_BLKS  M_        // 1024
#define BM_BLKS    B_        // 8 builder blocks
#define BM_WORDS   1600      // words per batch (50000/32 = 1563, padded)
#define GEMM_BLKS  3128

typedef __bf16 bf16x8 __attribute__((ext_vector_type(8)));
typedef float  f32x4  __attribute__((ext_vector_type(4)));
typedef unsigned short u16;
typedef unsigned short u16x8 __attribute__((ext_vector_type(8)));

__device__ __forceinline__ float bf2f(u16 u) {
    union { unsigned i; float f; } c; c.i = ((unsigned)u) << 16; return c.f;
}
__device__ __forceinline__ u16 f2bf(float f) {
    union { float f; unsigned i; } c; c.f = f;
    unsigned i = c.i;
    unsigned r = (i + 0x7FFFu + ((i >> 16) & 1u)) >> 16;   // round-nearest-even
    return (u16)r;
}

// block-wide reductions, blockDim.x == 256 (4 waves)
__device__ __forceinline__ float bsum(float v, float* sb) {
    #pragma unroll
    for (int o = 32; o; o >>= 1) v += __shfl_xor(v, o);
    __syncthreads();
    if ((threadIdx.x & 63) == 0) sb[threadIdx.x >> 6] = v;
    __syncthreads();
    return sb[0] + sb[1] + sb[2] + sb[3];
}

// K1 fused: [0,WCONV) proj_w f32->bf16 | [+MW) mw dots | [+ROWS) LN rows |
//           [+BM) per-batch: src bitmap + first-occurrence slot map
__global__ void k_pre(const float* __restrict__ pw, u16* __restrict__ wb,
                      const float* __restrict__ mem, const float* __restrict__ whw,
                      float* __restrict__ mw,
                      const float* __restrict__ x, const float* __restrict__ xt,
                      const float* __restrict__ attn,
                      const float* __restrict__ na, const float* __restrict__ nb,
                      const float* __restrict__ wsw, const float* __restrict__ wxw,
                      const float* __restrict__ whb, const float* __restrict__ wsb,
                      const float* __restrict__ wxb, const float* __restrict__ bp,
                      const int* __restrict__ src, unsigned* __restrict__ bm,
                      int* __restrict__ slot,
                      u16* __restrict__ Ab, float* __restrict__ pgen,
                      float* __restrict__ outp) {
    __shared__ float sb[4];
    __shared__ unsigned sbm[BM_WORDS];
    int bid = blockIdx.x;
    int tid = threadIdx.x;
    if (bid < WCONV_BLKS) {
        size_t i = ((size_t)bid * 256 + tid) * 8;
        float4 a = *(const float4*)(pw + i);
        float4 b = *(const float4*)(pw + i + 4);
        u16x8 o;
        o[0] = f2bf(a.x); o[1] = f2bf(a.y); o[2] = f2bf(a.z); o[3] = f2bf(a.w);
        o[4] = f2bf(b.x); o[5] = f2bf(b.y); o[6] = f2bf(b.z); o[7] = f2bf(b.w);
        *(u16x8*)(wb + i) = o;
        return;
    }
    if (bid < WCONV_BLKS + MW_BLKS) {
        int row = bid - WCONV_BLKS;               // b*S + s
        const float* mr = mem + (size_t)row * D_;
        float2 m2 = *(const float2*)(mr + tid * 2);
        float2 w2 = *(const float2*)(whw + tid * 2);
        float tot = bsum(m2.x * w2.x + m2.y * w2.y, sb);
        if (tid == 0) mw[row] = tot;
        return;
    }
    if (bid < WCONV_BLKS + MW_BLKS + ROWS_BLKS) {
        int row = bid - WCONV_BLKS - MW_BLKS;     // b*T + t
        int b = row / T_;
        const float* xr  = x  + (size_t)row * D_;
        const float* xtr = xt + (size_t)row * D_;
        float2 xv = *(const float2*)(xr + tid * 2);
        float tsx  = bsum(xv.x + xv.y, sb);
        float tsx2 = bsum(xv.x * xv.x + xv.y * xv.y, sb);
        float mu  = tsx / (float)D_;
        float var = fmaxf(tsx2 / (float)D_ - mu * mu, 0.f);
        float rs  = 1.f / (sqrtf(var) + EPS_LN);
        float2 nav = *(const float2*)(na + tid * 2);
        float2 nbv = *(const float2*)(nb + tid * 2);
        u16 a0 = f2bf(nav.x * (xv.x - mu) * rs + nbv.x);
        u16 a1 = f2bf(nav.y * (xv.y - mu) * rs + nbv.y);
        ((unsigned*)(Ab + (size_t)row * D_))[tid] = (unsigned)a0 | ((unsigned)a1 << 16);
        float2 wsv = *(const float2*)(wsw + tid * 2);
        float2 wxv = *(const float2*)(wxw + tid * 2);
        float2 xtv = *(const float2*)(xtr + tid * 2);
        float dot = xv.x * wsv.x + xv.y * wsv.y + xtv.x * wxv.x + xtv.y * wxv.y;
        if (tid < 200) {
            const float* ar  = attn + (size_t)row * S_;
            const float* mwb = mw + b * S_;
            float2 av = *(const float2*)(ar + tid * 2);
            float2 mv = *(const float2*)(mwb + tid * 2);
            dot += av.x * mv.x + av.y * mv.y;
        }
        float tdot = bsum(dot, sb);
        if (tid == 0) {
            float logit = tdot + whb[0] + wsb[0] + wxb[0] + bp[0];
            float p = 1.f / (1.f + __expf(-logit));
            pgen[row] = p;
            outp[row] = p;
        }
        return;
    }
    {   // builder: one block per batch b -> bitmap + slot (first occurrence)
        int b = bid - WCONV_BLKS - MW_BLKS - ROWS_BLKS;
        for (int i = tid; i < BM_WORDS; i += 256) sbm[i] = 0u;
        const int* sr = src + b * S_;
        int* sl = slot + (size_t)b * V_;
        for (int s = tid; s < S_; s += 256) sl[sr[s]] = 0x7fffffff;
        __syncthreads();                  // drains vmcnt: inits visible (L1 write-through)
        for (int s = tid; s < S_; s += 256) {
            int v = sr[s];
            atomicOr(&sbm[v >> 5], 1u << (v & 31));
            atomicMin(&sl[v], s);
        }
        __syncthreads();
        unsigned* dst = bm + b * BM_WORDS;
        for (int i = tid; i < BM_WORDS; i += 256) dst[i] = sbm[i];
    }
}

// K2: [0,GEMM_BLKS) GEMM blocks; [GEMM_BLKS,+M_) enc rider blocks.
// GEMM: 128x128 tile, 4 waves, depth-3 pipelined K-loop (best measured),
// ONE barrier per step, counted vmcnt, fragment-major LDS, fused sum-exp.
// enc rider (per row): enc[row][f] = sum_{s: slot[src[s]]==f} attn[row][s].
__global__ __launch_bounds__(256) void k_gemm(const u16* __restrict__ Ab,
                                              const u16* __restrict__ Wb,
                                              const float* __restrict__ projb,
                                              u16* __restrict__ dec,
                                              float* __restrict__ psum,
                                              const int* __restrict__ src,
                                              const float* __restrict__ attn,
                                              const int* __restrict__ slot,
                                              float* __restrict__ enc) {
    __shared__ __align__(16) char smem[49152];    // 3 x 16KB (A 8K + B 8K)
    int bid = blockIdx.x;
    int tid = threadIdx.x;
    if (bid >= GEMM_BLKS) {
        // ---- enc rider block: one per (b,t) row ----
        int row = bid - GEMM_BLKS;
        int b = row >> 7;
        float* sh_enc = (float*)smem;
        for (int s = tid; s < S_; s += 256) sh_enc[s] = 0.f;
        __syncthreads();
        const int* sr = src + b * S_;
        const int* sl = slot + (size_t)b * V_;
        const float* ar = attn + (size_t)row * S_;
        for (int s = tid; s < S_; s += 256)
            atomicAdd(&sh_enc[sl[sr[s]]], ar[s]);
        __syncthreads();
        float* er = enc + (size_t)row * S_;
        for (int s = tid; s < S_; s += 256) er[s] = sh_enc[s];
        return;
    }
    int xcd = bid & 7, loc = bid >> 3;
    int wg = xcd * NT_ + loc;             // bijective: 3128 = 8*391
    int mt = wg & 7, nt = wg >> 3;
    int brow = mt * 128, bcol = nt * 128;
    int lane = tid & 63, wv = tid >> 6;
    int wm = wv >> 1, wn = wv & 1;
    int kq = lane >> 4, lr = lane & 15;

    // per-thread staging source offsets (fragment-major pre-permutation, m173)
    size_t aoff[2], boff[2];
    int flatoff[2];
    #pragma unroll
    for (int i = 0; i < 2; ++i) {
        int flat = i * 4096 + tid * 16;            // bytes into 8KB half
        flatoff[i] = flat;
        int sub = flat >> 10;                      // 16-row subtile 0..7
        int l   = (flat >> 4) & 63;                // lane slot in subtile
        int kq2 = l >> 4, lr2 = l & 15;
        int arow = brow + sub * 16 + lr2;
        int vrow = bcol + sub * 16 + lr2; if (vrow >= V_) vrow = V_ - 1;
        aoff[i] = (size_t)arow * 512 + kq2 * 8;
        boff[i] = (size_t)vrow * 512 + kq2 * 8;
    }

#define STAGE(buf, kt) { \
    char* ab = smem + (buf) * 16384; \
    _Pragma("unroll") \
    for (int i = 0; i < 2; ++i) { \
        __builtin_amdgcn_global_load_lds( \
            (const __attribute__((address_space(1))) unsigned*)(Ab + aoff[i] + (size_t)(kt) * 32), \
            (__attribute__((address_space(3))) unsigned*)(ab + flatoff[i]), 16, 0, 0); \
        __builtin_amdgcn_global_load_lds( \
            (const __attribute__((address_space(1))) unsigned*)(Wb + boff[i] + (size_t)(kt) * 32), \
            (__attribute__((address_space(3))) unsigned*)(ab + 8192 + flatoff[i]), 16, 0, 0); \
    } }

    f32x4 acc[4][4] = {};
    STAGE(0, 0);
    STAGE(1, 1);
    STAGE(2, 2);                                   // 12 outstanding / thread
    asm volatile("s_waitcnt vmcnt(8)" ::: "memory");   // tile 0 landed
    __builtin_amdgcn_s_barrier();
    __builtin_amdgcn_sched_barrier(0);
    int cur = 0;
    for (int kt = 0; kt < 16; ++kt) {
        const bf16x8* Afp = (const bf16x8*)(smem + cur * 16384);
        const bf16x8* Bfp = (const bf16x8*)(smem + cur * 16384 + 8192);
        bf16x8 af[4], bfr[4];
        #pragma unroll
        for (int m = 0; m < 4; ++m) af[m]  = Afp[(wm * 4 + m) * 64 + lane];
        #pragma unroll
        for (int n = 0; n < 4; ++n) bfr[n] = Bfp[(wn * 4 + n) * 64 + lane];
        #pragma unroll
        for (int m = 0; m < 4; ++m)
            #pragma unroll
            for (int n = 0; n < 4; ++n)
                acc[m][n] = __builtin_amdgcn_mfma_f32_16x16x32_bf16(af[m], bfr[n], acc[m][n], 0, 0, 0);
        __builtin_amdgcn_sched_barrier(0);
        if (kt == 15) break;
        if (kt < 14) { asm volatile("s_waitcnt vmcnt(4)" ::: "memory"); }
        else         { asm volatile("s_waitcnt vmcnt(0)" ::: "memory"); }
        __builtin_amdgcn_s_barrier();
        __builtin_amdgcn_sched_barrier(0);
        if (kt < 13) STAGE(cur, kt + 3);
        cur = (cur == 2) ? 0 : cur + 1;
    }
#undef STAGE
    __syncthreads();                               // all frag reads done before Os reuse

    // epilogue: bias, sum-exp partials (no max: |dec| < ~8), Os staging for
    // coalesced stores
    float pbn[4]; int cvaln[4];
    #pragma unroll
    for (int n = 0; n < 4; ++n) {
        int col = bcol + wn * 64 + n * 16 + lr;
        cvaln[n] = (col < V_);
        pbn[n] = cvaln[n] ? projb[col] : 0.f;
    }
    u16 (*Os)[136] = (u16(*)[136])smem;
    float* ssum = (float*)(smem + 34816);          // [2][128]
    #pragma unroll
    for (int m = 0; m < 4; ++m) {
        #pragma unroll
        for (int i = 0; i < 4; ++i) {
            int row128 = wm * 64 + m * 16 + kq * 4 + i;
            float se = 0.f;
            #pragma unroll
            for (int n = 0; n < 4; ++n) {
                float dv = acc[m][n][i] + pbn[n];
                if (cvaln[n]) se += __expf(dv);
                Os[row128][wn * 64 + n * 16 + lr] = f2bf(dv);
            }
            #pragma unroll
            for (int o = 1; o < 16; o <<= 1) se += __shfl_xor(se, o);
            if (lr == 0) ssum[wn * 128 + row128] = se;
        }
    }
    __syncthreads();
    if (tid < 128) {
        psum[(size_t)(brow + tid) * NT_ + nt] = ssum[tid] + ssum[128 + tid];
    }
    #pragma unroll
    for (int j = 0; j < 8; ++j) {
        int row = j * 16 + (tid >> 4);
        int c8 = (tid & 15) * 8;
        int gcol = bcol + c8;
        if (gcol + 8 <= V_) {                      // V_ % 8 == 0: chunk all-or-nothing
            u16x8 v = *(const u16x8*)&Os[row][c8];
            *(u16x8*)(dec + (size_t)(brow + row) * V_ + gcol) = v;
        }
    }
}

// K3: single-writer final. out = d + C everywhere EXCEPT src columns, which
// get the exact pointer-mix value computed IN-REGISTER (stores stay float4).
__global__ void k_post(const u16* __restrict__ dec, const float* __restrict__ pgen,
                       const float* __restrict__ psum, const unsigned* __restrict__ bm,
                       const int* __restrict__ slot, const float* __restrict__ enc,
                       float* __restrict__ out) {
    __shared__ float sb[4];
    int bid = blockIdx.x;
    int tid = threadIdx.x;
    int c = bid % 25, row = bid / 25;
    int b = row >> 7;
    const float* ps = psum + (size_t)row * NT_;
    float s = 0.f;
    for (int j = tid; j < NT_; j += 256) s += ps[j];
    s = bsum(s, sb);
    float bs = __logf(s);
    float p  = pgen[row];
    float C  = __logf(p) - bs;
    int v0 = c * 2048 + tid * 8;
    if (v0 >= V_) return;
    unsigned w = bm[b * BM_WORDS + (v0 >> 5)];
    unsigned mask = (w >> ((tid & 3) * 8)) & 0xFFu;
    u16x8 d = *(const u16x8*)(dec + (size_t)row * V_ + v0);
    float o[8];
    bool rare = false;
    #pragma unroll
    for (int j = 0; j < 8; ++j) {
        o[j] = bf2f(d[j]) + C;
        rare |= (o[j] < -24.f);
    }
    if (__any(rare)) {                    // wave-uniform: skipped ~always
        #pragma unroll
        for (int j = 0; j < 8; ++j)
            if (o[j] < -24.f) o[j] = __logf(__expf(o[j]) + 1e-12f);
    }
    if (mask) {                           // few lanes per wave: VALU fixup only
        const int* sl = slot + (size_t)b * V_;
        const float* er = enc + (size_t)row * S_;
        #pragma unroll
        for (int j = 0; j < 8; ++j) {
            if ((mask >> j) & 1u) {
                float e = er[sl[v0 + j]];
                float dv = bf2f(d[j]);
                o[j] = __logf(p * __expf(dv - bs) + (1.f - p) * e + 1e-12f);
            }
        }
    }
    float* op = out + (size_t)row * V_ + v0;
    float4 o0, o1;
    o0.x = o[0]; o0.y = o[1]; o0.z = o[2]; o0.w = o[3];
    o1.x = o[4]; o1.y = o[5]; o1.z = o[6]; o1.w = o[7];
    *(float4*)op = o0;
    *(float4*)(op + 4) = o1;
}

extern "C" void kernel_launch(void* const* d_in, const int* in_sizes, int n_in,
                              void* d_out, int out_size, void* d_ws, size_t ws_size,
                              hipStream_t stream) {
    const float* x    = (const float*)d_in[0];
    const float* xt   = (const float*)d_in[1];
    const float* mem  = (const float*)d_in[2];
    const float* attn = (const float*)d_in[3];
    const int*   src  = (const int*)d_in[4];
    const float* na   = (const float*)d_in[5];
    const float* nb   = (const float*)d_in[6];
    const float* pw   = (const float*)d_in[7];
    const float* pb   = (const float*)d_in[8];
    const float* whw  = (const float*)d_in[9];
    const float* whb  = (const float*)d_in[10];
    const float* wsw  = (const float*)d_in[11];
    const float* wsb  = (const float*)d_in[12];
    const float* wxw  = (const float*)d_in[13];
    const float* wxb  = (const float*)d_in[14];
    const float* bp   = (const float*)d_in[15];

    char* ws = (char*)d_ws;
    u16*     Wb   = (u16*)(ws + 0);               // 51,200,000 B
    u16*     Ab   = (u16*)(ws + 51200000);        //  1,048,576 B
    u16*     dec  = (u16*)(ws + 52248576);        // 102,400,000 B
    float*   psum = (float*)(ws + 154648576);     //  1,601,536 B
    float*   mw   = (float*)(ws + 156250112);     //     12,800 B
    float*   pgen = (float*)(ws + 156262912);     //      4,096 B
    unsigned* bmp = (unsigned*)(ws + 156267008);  //     51,200 B
    int*     slot = (int*)(ws + 156318208);       //  1,600,000 B
    float*   enc  = (float*)(ws + 157918208);     //  1,638,400 B
    float* out  = (float*)d_out;
    float* outp = out + (size_t)M_ * V_;          // p_gen section

    k_pre <<<WCONV_BLKS + MW_BLKS + ROWS_BLKS + BM_BLKS, 256, 0, stream>>>(
              pw, Wb, mem, whw, mw, x, xt, attn, na, nb,
              wsw, wxw, whb, wsb, wxb, bp, src, bmp, slot, Ab, pgen, outp);
    k_gemm<<<GEMM_BLKS + M_, 256, 0, stream>>>(Ab, Wb, pb, dec, psum,
                                               src, attn, slot, enc);
    k_post<<<25 * M_, 256, 0, stream>>>(dec, pgen, psum, bmp, slot, enc, out);
}